// Round 6
// baseline (2180.038 us; speedup 1.0000x reference)
//
#include <hip/hip_runtime.h>
#include <math.h>

// Problem constants (fixed by reference)
#define S_LEN    1024
#define NHEAD    16
#define DHEAD    128
#define HIDDEN   2048
#define BATCH    2
#define BH       32            // BATCH*NHEAD
#define CACHE_B  204           // heavy+recent budget
#define RECENT_B 102
#define QK_SCALE 0.08838834764831845f   // 1/sqrt(128)

// ---------------------------------------------------------------------------
// Tiled fp32 GEMM, 128x128 tile, 256 threads, 8x8 per thread.
// Fragment split rows {ty*4, 64+ty*4}, cols {tx*4, 64+tx*4}: all LDS reads
// are <=2-way bank aliased (free on CDNA4); pad 132 makes As stores 2-way.
// MODE 0: C = hs @ {wq|wk|wv} (blockIdx.z), epilogue scatters to [B,H,S,D].
// MODE 1: plain row-major C = A @ B0.
// ---------------------------------------------------------------------------
template <int MODE>
__global__ __launch_bounds__(256) void gemm_f32(
    const float* __restrict__ A, const float* __restrict__ B0,
    const float* __restrict__ B1, const float* __restrict__ B2,
    float* __restrict__ C0, float* __restrict__ C1, float* __restrict__ C2) {
  __shared__ float As[16][132];
  __shared__ float Bs[16][132];
  const float* Bm;
  float* C;
  if (MODE == 0) {
    int z = blockIdx.z;
    Bm = (z == 0) ? B0 : ((z == 1) ? B1 : B2);
    C = (z == 0) ? C0 : ((z == 1) ? C1 : C2);
  } else {
    Bm = B0;
    C = C0;
  }
  const int tid = threadIdx.x;
  const int tx = tid & 15, ty = tid >> 4;
  const int m0 = blockIdx.y * 128, n0 = blockIdx.x * 128;

  float acc[8][8];
#pragma unroll
  for (int i = 0; i < 8; ++i)
#pragma unroll
    for (int j = 0; j < 8; ++j) acc[i][j] = 0.0f;

  for (int k0 = 0; k0 < HIDDEN; k0 += 16) {
#pragma unroll
    for (int l = 0; l < 2; ++l) {
      int f = tid + l * 256;
      int r = f >> 2, c = (f & 3) * 4;
      const float4 a =
          *(const float4*)&A[(size_t)(m0 + r) * HIDDEN + k0 + c];
      As[c + 0][r] = a.x;
      As[c + 1][r] = a.y;
      As[c + 2][r] = a.z;
      As[c + 3][r] = a.w;
    }
#pragma unroll
    for (int l = 0; l < 2; ++l) {
      int f = tid + l * 256;
      int r = f >> 5, c = (f & 31) * 4;
      *(float4*)&Bs[r][c] =
          *(const float4*)&Bm[(size_t)(k0 + r) * HIDDEN + n0 + c];
    }
    __syncthreads();
#pragma unroll
    for (int kk = 0; kk < 16; ++kk) {
      float av[8], bv[8];
      *(float4*)&av[0] = *(float4*)&As[kk][ty * 4];
      *(float4*)&av[4] = *(float4*)&As[kk][64 + ty * 4];
      *(float4*)&bv[0] = *(float4*)&Bs[kk][tx * 4];
      *(float4*)&bv[4] = *(float4*)&Bs[kk][64 + tx * 4];
#pragma unroll
      for (int i = 0; i < 8; ++i)
#pragma unroll
        for (int j = 0; j < 8; ++j) acc[i][j] += av[i] * bv[j];
    }
    __syncthreads();
  }

#pragma unroll
  for (int gi = 0; gi < 2; ++gi)
#pragma unroll
    for (int i = 0; i < 4; ++i) {
      const int m = m0 + gi * 64 + ty * 4 + i;
#pragma unroll
      for (int gj = 0; gj < 2; ++gj) {
        const int n = n0 + gj * 64 + tx * 4;
        float4 o;
        o.x = acc[gi * 4 + i][gj * 4 + 0];
        o.y = acc[gi * 4 + i][gj * 4 + 1];
        o.z = acc[gi * 4 + i][gj * 4 + 2];
        o.w = acc[gi * 4 + i][gj * 4 + 3];
        if (MODE == 0) {
          const int b = m >> 10, s = m & (S_LEN - 1);
          const int h = n >> 7, d = n & (DHEAD - 1);
          *(float4*)&C[(((size_t)(b * NHEAD + h) * S_LEN + s) * DHEAD) + d] = o;
        } else {
          *(float4*)&C[(size_t)m * HIDDEN + n] = o;
        }
      }
    }
}

// ---------------------------------------------------------------------------
// RoPE in place on Q,K ([BH,S,D] layout).
// ---------------------------------------------------------------------------
__global__ __launch_bounds__(256) void rope_qk(float* __restrict__ Q,
                                               float* __restrict__ K) {
  int g = blockIdx.x * 4 + (threadIdx.x >> 6);  // row id over BH*S
  int lane = threadIdx.x & 63;
  int s = g & (S_LEN - 1);
  double invf = exp(-((double)(2 * lane) / 128.0) * log(10000.0));
  float angle = (float)s * (float)invf;
  float c = (float)cos((double)angle);
  float sn = (float)sin((double)angle);
  size_t base = (size_t)g * DHEAD;
  float q0 = Q[base + lane], q1 = Q[base + lane + 64];
  Q[base + lane] = q0 * c - q1 * sn;
  Q[base + lane + 64] = q1 * c + q0 * sn;
  float k0 = K[base + lane], k1 = K[base + lane + 64];
  K[base + lane] = k0 * c - k1 * sn;
  K[base + lane + 64] = k1 * c + k0 * sn;
}

// ---------------------------------------------------------------------------
// Per (b,h): mean |k| over first 204 roped tokens, stable argsort rank,
// keep top-6 dims; pack Qp/Kp[bh][s][0..5] (stride 8).
// ---------------------------------------------------------------------------
__global__ __launch_bounds__(128) void keep_pack(
    const float* __restrict__ Q, const float* __restrict__ K,
    float* __restrict__ Qp, float* __restrict__ Kp) {
  int bh = blockIdx.x;
  int d = threadIdx.x;
  __shared__ float ma[128];
  __shared__ int kf[128];
  __shared__ int kidx[8];
  const float* Kb = K + (size_t)bh * S_LEN * DHEAD;
  const float* Qb = Q + (size_t)bh * S_LEN * DHEAD;
  float sum = 0.0f;
  for (int s = 0; s < CACHE_B; ++s) sum += fabsf(Kb[(size_t)s * DHEAD + d]);
  ma[d] = sum / 204.0f;
  __syncthreads();
  float v = ma[d];
  int rank = 0;
  for (int e = 0; e < 128; ++e) {
    float u = ma[e];
    rank += (u < v) || (u == v && e < d);  // stable-argsort rank
  }
  int keep = (rank >= 128 - 6);
  kf[d] = keep;
  __syncthreads();
  if (keep) {
    int pos = 0;
    for (int e = 0; e < d; ++e) pos += kf[e];
    kidx[pos] = d;
  }
  __syncthreads();
  int i0 = kidx[0], i1 = kidx[1], i2 = kidx[2];
  int i3 = kidx[3], i4 = kidx[4], i5 = kidx[5];
  for (int s = threadIdx.x; s < S_LEN; s += 128) {
    size_t src = (size_t)s * DHEAD;
    size_t dst = ((size_t)bh * S_LEN + s) * 8;
    Qp[dst + 0] = Qb[src + i0]; Qp[dst + 1] = Qb[src + i1];
    Qp[dst + 2] = Qb[src + i2]; Qp[dst + 3] = Qb[src + i3];
    Qp[dst + 4] = Qb[src + i4]; Qp[dst + 5] = Qb[src + i5];
    Kp[dst + 0] = Kb[src + i0]; Kp[dst + 1] = Kb[src + i1];
    Kp[dst + 2] = Kb[src + i2]; Kp[dst + 3] = Kb[src + i3];
    Kp[dst + 4] = Kb[src + i4]; Kp[dst + 5] = Kb[src + i5];
  }
}

// ---------------------------------------------------------------------------
// Batched A_full[bh][t][s] = QK_SCALE * Q[t]·K[s], lower-triangular tiles
// only. Same conflict-free fragment split as gemm_f32.
// ---------------------------------------------------------------------------
__global__ __launch_bounds__(256) void qkt_scores(
    const float* __restrict__ Q, const float* __restrict__ K,
    float* __restrict__ Af) {
  if (blockIdx.x > blockIdx.y) return;  // strictly-upper tiles never read
  __shared__ float Qs[16][132];
  __shared__ float Ks[16][132];
  const int bh = blockIdx.z;
  const int tid = threadIdx.x;
  const int tx = tid & 15, ty = tid >> 4;
  const int m0 = blockIdx.y * 128, n0 = blockIdx.x * 128;
  const float* Qb = Q + (size_t)bh * S_LEN * DHEAD;
  const float* Kb = K + (size_t)bh * S_LEN * DHEAD;
  float acc[8][8];
#pragma unroll
  for (int i = 0; i < 8; ++i)
#pragma unroll
    for (int j = 0; j < 8; ++j) acc[i][j] = 0.0f;

  for (int k0 = 0; k0 < DHEAD; k0 += 16) {
#pragma unroll
    for (int l = 0; l < 2; ++l) {
      int f = tid + l * 256;
      int r = f >> 2, c = (f & 3) * 4;
      const float4 q = *(const float4*)&Qb[(size_t)(m0 + r) * DHEAD + k0 + c];
      Qs[c + 0][r] = q.x; Qs[c + 1][r] = q.y;
      Qs[c + 2][r] = q.z; Qs[c + 3][r] = q.w;
      const float4 kv = *(const float4*)&Kb[(size_t)(n0 + r) * DHEAD + k0 + c];
      Ks[c + 0][r] = kv.x; Ks[c + 1][r] = kv.y;
      Ks[c + 2][r] = kv.z; Ks[c + 3][r] = kv.w;
    }
    __syncthreads();
#pragma unroll
    for (int kk = 0; kk < 16; ++kk) {
      float av[8], bv[8];
      *(float4*)&av[0] = *(float4*)&Qs[kk][ty * 4];
      *(float4*)&av[4] = *(float4*)&Qs[kk][64 + ty * 4];
      *(float4*)&bv[0] = *(float4*)&Ks[kk][tx * 4];
      *(float4*)&bv[4] = *(float4*)&Ks[kk][64 + tx * 4];
#pragma unroll
      for (int i = 0; i < 8; ++i)
#pragma unroll
        for (int j = 0; j < 8; ++j) acc[i][j] += av[i] * bv[j];
    }
    __syncthreads();
  }
  float* Cb = Af + (size_t)bh * S_LEN * S_LEN;
#pragma unroll
  for (int gi = 0; gi < 2; ++gi)
#pragma unroll
    for (int i = 0; i < 4; ++i) {
      const int t = m0 + gi * 64 + ty * 4 + i;
#pragma unroll
      for (int gj = 0; gj < 2; ++gj) {
        const int s = n0 + gj * 64 + tx * 4;
        float4 o;
        o.x = acc[gi * 4 + i][gj * 4 + 0] * QK_SCALE;
        o.y = acc[gi * 4 + i][gj * 4 + 1] * QK_SCALE;
        o.z = acc[gi * 4 + i][gj * 4 + 2] * QK_SCALE;
        o.w = acc[gi * 4 + i][gj * 4 + 3] * QK_SCALE;
        *(float4*)&Cb[(size_t)t * S_LEN + s] = o;
      }
    }
}

// ---------------------------------------------------------------------------
// Sequential H2O eviction scan — producer/consumer wave specialization.
// 2 waves per (b,h). Wave 0 (producer) streams 8-row chunks of A into a
// double-buffered LDS ring via global_load_lds width=16 (no VGPR round-trip;
// all 32 DMAs per chunk in flight, drained once by the compiler's own
// vmcnt(0)+barrier). Wave 1 (consumer) runs the 8 sequential argmin steps
// per chunk from LDS. Load latency lives on a different wave than the
// serial chain, so compiler load-sinking (rounds 2-4 failure) cannot hurt.
// Argmin per step: flush ineligible to +inf, fp32 min tree + 6-stage
// butterfly; then exact first-index pass (fl==best -> min s) — identical
// semantics to jnp.argmin incl. first-index ties.
// Rows consumed: t-1 for t=205..1023 (i.e. rows 204..1022), 103 chunks.
// ---------------------------------------------------------------------------
#define SE_CHUNK  8
#define SE_NCHUNK 103

__device__ __forceinline__ void async_copy16(const float* gsrc, float* ldst) {
  __builtin_amdgcn_global_load_lds(
      (const __attribute__((address_space(1))) void*)gsrc,
      (__attribute__((address_space(3))) void*)ldst, 16, 0, 0);
}

__global__ __launch_bounds__(128, 1) void scan_evict(
    const float* __restrict__ Af, int* __restrict__ evt) {
  __shared__ float buf[2][SE_CHUNK][S_LEN];
  const int bh = blockIdx.x;
  const int tid = threadIdx.x;
  const int lane = tid & 63;
  const int wv = tid >> 6;  // 0 = producer, 1 = consumer
  const float* Ab = Af + (size_t)bh * S_LEN * S_LEN;
  int* evtb = evt + bh * S_LEN;

  // lane-owned s values: s = p*256 + lane*4 + q  (slot b = p*4+q)
  int slow[16];
#pragma unroll
  for (int p = 0; p < 4; ++p)
#pragma unroll
    for (int q = 0; q < 4; ++q) slow[p * 4 + q] = p * 256 + lane * 4 + q;
  unsigned evmask = 0;

  if (wv == 1) {
    int4* e4 = (int4*)evtb;
    const int4 big = make_int4(0x7fffffff, 0x7fffffff, 0x7fffffff, 0x7fffffff);
#pragma unroll
    for (int j = 0; j < 4; ++j) e4[j * 64 + lane] = big;
  } else {
    // prologue: stage chunk 0 (rows 204..211) into buf[0]
#pragma unroll
    for (int u = 0; u < SE_CHUNK; ++u) {
      const float* rb = Ab + (size_t)(204 + u) * S_LEN;
#pragma unroll
      for (int p = 0; p < 4; ++p)
        async_copy16(rb + p * 256 + lane * 4, &buf[0][u][p * 256]);
    }
  }
  __syncthreads();

  for (int c = 0; c < SE_NCHUNK; ++c) {
    if (wv == 0) {
      if (c + 1 < SE_NCHUNK) {
        const int nb = (c + 1) & 1;
#pragma unroll
        for (int u = 0; u < SE_CHUNK; ++u) {
          int row = 204 + (c + 1) * SE_CHUNK + u;
          row = row > 1022 ? 1022 : row;  // last chunk: clamp (never consumed)
          const float* rb = Ab + (size_t)row * S_LEN;
#pragma unroll
          for (int p = 0; p < 4; ++p)
            async_copy16(rb + p * 256 + lane * 4, &buf[nb][u][p * 256]);
        }
      }
    } else {
#pragma unroll
      for (int u = 0; u < SE_CHUNK; ++u) {
        const int t = 205 + c * SE_CHUNK + u;
        if (t > 1023) break;
        const int limit = t - RECENT_B;
        float fl[16];
        float best = INFINITY;
#pragma unroll
        for (int p = 0; p < 4; ++p) {
          const float4 f = *(const float4*)&buf[c & 1][u][p * 256 + lane * 4];
          const float e[4] = {f.x, f.y, f.z, f.w};
#pragma unroll
          for (int q = 0; q < 4; ++q) {
            const int b = p * 4 + q;
            const bool ok = (slow[b] < limit) && !((evmask >> b) & 1u);
            fl[b] = ok ? e[q] : INFINITY;
            best = fminf(best, fl[b]);
          }
        }
#pragma unroll
        for (int off = 32; off; off >>= 1)
          best = fminf(best, __shfl_xor(best, off, 64));
        int cand = 0x7fffffff;
#pragma unroll
        for (int b = 0; b < 16; ++b)
          if (fl[b] == best) cand = min(cand, slow[b]);
#pragma unroll
        for (int off = 32; off; off >>= 1)
          cand = min(cand, __shfl_xor(cand, off, 64));
        if (((cand & 255) >> 2) == lane)
          evmask |= 1u << (((cand >> 8) << 2) | (cand & 3));
        if (lane == 0) evtb[cand] = t;
      }
    }
    __syncthreads();
  }
}

// ---------------------------------------------------------------------------
// Final attention: 8 query rows per workgroup. Phase 1 (wave per 2 rows):
// score = evicted(s by time t) ? QK_SCALE*dot6(Qp,Kp) : A_full[t][s];
// softmax -> P in LDS + 1/sum. Phase 2: out = (P·V)/sum -> [B,S,HID].
// ---------------------------------------------------------------------------
__global__ __launch_bounds__(256) void attn_av(
    const float* __restrict__ Af, const float* __restrict__ Qp,
    const float* __restrict__ Kp, const int* __restrict__ evt,
    const float* __restrict__ V, float* __restrict__ AO) {
  const int t0 = blockIdx.x * 8;
  const int bh = blockIdx.y;
  __shared__ float P[8][S_LEN];
  __shared__ float rinv[8];
  const int tid = threadIdx.x;
  const int lane = tid & 63, wave = tid >> 6;
  const float* Ab = Af + (size_t)bh * S_LEN * S_LEN;
  const int* eb = evt + bh * S_LEN;
  const float* Kpb = Kp + (size_t)bh * S_LEN * 8;

  for (int rr = 0; rr < 2; ++rr) {
    const int r = wave * 2 + rr;
    const int t = t0 + r;
    float qp[6];
#pragma unroll
    for (int j = 0; j < 6; ++j) qp[j] = Qp[((size_t)bh * S_LEN + t) * 8 + j];
    float vals[16];
    float m = -INFINITY;
#pragma unroll
    for (int i = 0; i < 16; ++i) {
      int s = lane + i * 64;
      float sc = 0.0f;
      if (s <= t) {
        if (eb[s] <= t) {
          const float* kr = &Kpb[(size_t)s * 8];
          sc = QK_SCALE * (qp[0] * kr[0] + qp[1] * kr[1] + qp[2] * kr[2] +
                           qp[3] * kr[3] + qp[4] * kr[4] + qp[5] * kr[5]);
        } else {
          sc = Ab[(size_t)t * S_LEN + s];
        }
        m = fmaxf(m, sc);
      }
      vals[i] = sc;
    }
    for (int off = 32; off; off >>= 1) m = fmaxf(m, __shfl_xor(m, off, 64));
    float sum = 0.0f;
#pragma unroll
    for (int i = 0; i < 16; ++i) {
      int s = lane + i * 64;
      float p = 0.0f;
      if (s <= t) {
        p = expf(vals[i] - m);
        sum += p;
      }
      P[r][s] = p;
    }
    for (int off = 32; off; off >>= 1) sum += __shfl_xor(sum, off, 64);
    if (lane == 0) rinv[r] = 1.0f / sum;
  }
  __syncthreads();

  const int d4 = (tid & 31) * 4;
  const int r = tid >> 5;
  const int t = t0 + r;
  const float* Vb = V + (size_t)bh * S_LEN * DHEAD;
  float ax = 0.f, ay = 0.f, az = 0.f, aw = 0.f;
  const int smax = t0 + 7;
  for (int s4 = 0; s4 <= smax; s4 += 4) {
    const float4 p4 = *(const float4*)&P[r][s4];
    const float4 v0 = *(const float4*)&Vb[(size_t)(s4 + 0) * DHEAD + d4];
    const float4 v1 = *(const float4*)&Vb[(size_t)(s4 + 1) * DHEAD + d4];
    const float4 v2 = *(const float4*)&Vb[(size_t)(s4 + 2) * DHEAD + d4];
    const float4 v3 = *(const float4*)&Vb[(size_t)(s4 + 3) * DHEAD + d4];
    ax += p4.x * v0.x + p4.y * v1.x + p4.z * v2.x + p4.w * v3.x;
    ay += p4.x * v0.y + p4.y * v1.y + p4.z * v2.y + p4.w * v3.y;
    az += p4.x * v0.z + p4.y * v1.z + p4.z * v2.z + p4.w * v3.z;
    aw += p4.x * v0.w + p4.y * v1.w + p4.z * v2.w + p4.w * v3.w;
  }
  const float ri = rinv[r];
  const int b = bh >> 4, h = bh & 15;
  float4 o;
  o.x = ax * ri; o.y = ay * ri; o.z = az * ri; o.w = aw * ri;
  *(float4*)&AO[((size_t)(b * S_LEN + t)) * HIDDEN + h * DHEAD + d4] = o;
}

// ---------------------------------------------------------------------------
extern "C" void kernel_launch(void* const* d_in, const int* in_sizes, int n_in,
                              void* d_out, int out_size, void* d_ws,
                              size_t ws_size, hipStream_t stream) {
  const float* hs = (const float*)d_in[0];
  const float* wq = (const float*)d_in[1];
  const float* wk = (const float*)d_in[2];
  const float* wv = (const float*)d_in[3];
  const float* wo = (const float*)d_in[4];
  float* out = (float*)d_out;

  const size_t SZ_QKV = (size_t)BH * S_LEN * DHEAD;
  float* Q = (float*)d_ws;
  float* K = Q + SZ_QKV;
  float* V = K + SZ_QKV;
  float* Af = V + SZ_QKV;
  float* Qp = Af + (size_t)BH * S_LEN * S_LEN;
  float* Kp = Qp + (size_t)BH * S_LEN * 8;
  int* evt = (int*)(Kp + (size_t)BH * S_LEN * 8);
  float* AO = (float*)(evt + BH * S_LEN);

  gemm_f32<0><<<dim3(16, 16, 3), 256, 0, stream>>>(hs, wq, wk, wv, Q, K, V);
  rope_qk<<<dim3(BH * S_LEN / 4), 256, 0, stream>>>(Q, K);
  keep_pack<<<dim3(BH), 128, 0, stream>>>(Q, K, Qp, Kp);
  qkt_scores<<<dim3(8, 8, BH), 256, 0, stream>>>(Q, K, Af);
  scan_evict<<<dim3(BH), 128, 0, stream>>>(Af, evt);
  attn_av<<<dim3(S_LEN / 8, BH), 256, 0, stream>>>(Af, Qp, Kp, evt, V, AO);
  gemm_f32<1><<<dim3(16, 16, 1), 256, 0, stream>>>(AO, wo, nullptr, nullptr,
                                                   out, nullptr, nullptr);
}

// Round 7
// 2000.951 us; speedup vs baseline: 1.0895x; 1.0895x over previous
//
#include <hip/hip_runtime.h>
#include <math.h>

// Problem constants (fixed by reference)
#define S_LEN    1024
#define NHEAD    16
#define DHEAD    128
#define HIDDEN   2048
#define BATCH    2
#define BH       32            // BATCH*NHEAD
#define CACHE_B  204           // heavy+recent budget
#define RECENT_B 102
#define QK_SCALE 0.08838834764831845f   // 1/sqrt(128)

// ---------------------------------------------------------------------------
// Tiled fp32 GEMM, 128x128 tile, 256 threads, 8x8 per thread.
// Fragment split rows {ty*4, 64+ty*4}, cols {tx*4, 64+tx*4}: all LDS reads
// are <=2-way bank aliased (free on CDNA4); pad 132 makes As stores 2-way.
// MODE 0: C = hs @ {wq|wk|wv} (blockIdx.z), epilogue scatters to [B,H,S,D].
// MODE 1: plain row-major C = A @ B0.
// ---------------------------------------------------------------------------
template <int MODE>
__global__ __launch_bounds__(256) void gemm_f32(
    const float* __restrict__ A, const float* __restrict__ B0,
    const float* __restrict__ B1, const float* __restrict__ B2,
    float* __restrict__ C0, float* __restrict__ C1, float* __restrict__ C2) {
  __shared__ float As[16][132];
  __shared__ float Bs[16][132];
  const float* Bm;
  float* C;
  if (MODE == 0) {
    int z = blockIdx.z;
    Bm = (z == 0) ? B0 : ((z == 1) ? B1 : B2);
    C = (z == 0) ? C0 : ((z == 1) ? C1 : C2);
  } else {
    Bm = B0;
    C = C0;
  }
  const int tid = threadIdx.x;
  const int tx = tid & 15, ty = tid >> 4;
  const int m0 = blockIdx.y * 128, n0 = blockIdx.x * 128;

  float acc[8][8];
#pragma unroll
  for (int i = 0; i < 8; ++i)
#pragma unroll
    for (int j = 0; j < 8; ++j) acc[i][j] = 0.0f;

  for (int k0 = 0; k0 < HIDDEN; k0 += 16) {
#pragma unroll
    for (int l = 0; l < 2; ++l) {
      int f = tid + l * 256;
      int r = f >> 2, c = (f & 3) * 4;
      const float4 a =
          *(const float4*)&A[(size_t)(m0 + r) * HIDDEN + k0 + c];
      As[c + 0][r] = a.x;
      As[c + 1][r] = a.y;
      As[c + 2][r] = a.z;
      As[c + 3][r] = a.w;
    }
#pragma unroll
    for (int l = 0; l < 2; ++l) {
      int f = tid + l * 256;
      int r = f >> 5, c = (f & 31) * 4;
      *(float4*)&Bs[r][c] =
          *(const float4*)&Bm[(size_t)(k0 + r) * HIDDEN + n0 + c];
    }
    __syncthreads();
#pragma unroll
    for (int kk = 0; kk < 16; ++kk) {
      float av[8], bv[8];
      *(float4*)&av[0] = *(float4*)&As[kk][ty * 4];
      *(float4*)&av[4] = *(float4*)&As[kk][64 + ty * 4];
      *(float4*)&bv[0] = *(float4*)&Bs[kk][tx * 4];
      *(float4*)&bv[4] = *(float4*)&Bs[kk][64 + tx * 4];
#pragma unroll
      for (int i = 0; i < 8; ++i)
#pragma unroll
        for (int j = 0; j < 8; ++j) acc[i][j] += av[i] * bv[j];
    }
    __syncthreads();
  }

#pragma unroll
  for (int gi = 0; gi < 2; ++gi)
#pragma unroll
    for (int i = 0; i < 4; ++i) {
      const int m = m0 + gi * 64 + ty * 4 + i;
#pragma unroll
      for (int gj = 0; gj < 2; ++gj) {
        const int n = n0 + gj * 64 + tx * 4;
        float4 o;
        o.x = acc[gi * 4 + i][gj * 4 + 0];
        o.y = acc[gi * 4 + i][gj * 4 + 1];
        o.z = acc[gi * 4 + i][gj * 4 + 2];
        o.w = acc[gi * 4 + i][gj * 4 + 3];
        if (MODE == 0) {
          const int b = m >> 10, s = m & (S_LEN - 1);
          const int h = n >> 7, d = n & (DHEAD - 1);
          *(float4*)&C[(((size_t)(b * NHEAD + h) * S_LEN + s) * DHEAD) + d] = o;
        } else {
          *(float4*)&C[(size_t)m * HIDDEN + n] = o;
        }
      }
    }
}

// ---------------------------------------------------------------------------
// RoPE in place on Q,K ([BH,S,D] layout).
// ---------------------------------------------------------------------------
__global__ __launch_bounds__(256) void rope_qk(float* __restrict__ Q,
                                               float* __restrict__ K) {
  int g = blockIdx.x * 4 + (threadIdx.x >> 6);  // row id over BH*S
  int lane = threadIdx.x & 63;
  int s = g & (S_LEN - 1);
  double invf = exp(-((double)(2 * lane) / 128.0) * log(10000.0));
  float angle = (float)s * (float)invf;
  float c = (float)cos((double)angle);
  float sn = (float)sin((double)angle);
  size_t base = (size_t)g * DHEAD;
  float q0 = Q[base + lane], q1 = Q[base + lane + 64];
  Q[base + lane] = q0 * c - q1 * sn;
  Q[base + lane + 64] = q1 * c + q0 * sn;
  float k0 = K[base + lane], k1 = K[base + lane + 64];
  K[base + lane] = k0 * c - k1 * sn;
  K[base + lane + 64] = k1 * c + k0 * sn;
}

// ---------------------------------------------------------------------------
// Per (b,h): mean |k| over first 204 roped tokens, stable argsort rank,
// keep top-6 dims; pack Qp/Kp[bh][s][0..5] (stride 8).
// ---------------------------------------------------------------------------
__global__ __launch_bounds__(128) void keep_pack(
    const float* __restrict__ Q, const float* __restrict__ K,
    float* __restrict__ Qp, float* __restrict__ Kp) {
  int bh = blockIdx.x;
  int d = threadIdx.x;
  __shared__ float ma[128];
  __shared__ int kf[128];
  __shared__ int kidx[8];
  const float* Kb = K + (size_t)bh * S_LEN * DHEAD;
  const float* Qb = Q + (size_t)bh * S_LEN * DHEAD;
  float sum = 0.0f;
  for (int s = 0; s < CACHE_B; ++s) sum += fabsf(Kb[(size_t)s * DHEAD + d]);
  ma[d] = sum / 204.0f;
  __syncthreads();
  float v = ma[d];
  int rank = 0;
  for (int e = 0; e < 128; ++e) {
    float u = ma[e];
    rank += (u < v) || (u == v && e < d);  // stable-argsort rank
  }
  int keep = (rank >= 128 - 6);
  kf[d] = keep;
  __syncthreads();
  if (keep) {
    int pos = 0;
    for (int e = 0; e < d; ++e) pos += kf[e];
    kidx[pos] = d;
  }
  __syncthreads();
  int i0 = kidx[0], i1 = kidx[1], i2 = kidx[2];
  int i3 = kidx[3], i4 = kidx[4], i5 = kidx[5];
  for (int s = threadIdx.x; s < S_LEN; s += 128) {
    size_t src = (size_t)s * DHEAD;
    size_t dst = ((size_t)bh * S_LEN + s) * 8;
    Qp[dst + 0] = Qb[src + i0]; Qp[dst + 1] = Qb[src + i1];
    Qp[dst + 2] = Qb[src + i2]; Qp[dst + 3] = Qb[src + i3];
    Qp[dst + 4] = Qb[src + i4]; Qp[dst + 5] = Qb[src + i5];
    Kp[dst + 0] = Kb[src + i0]; Kp[dst + 1] = Kb[src + i1];
    Kp[dst + 2] = Kb[src + i2]; Kp[dst + 3] = Kb[src + i3];
    Kp[dst + 4] = Kb[src + i4]; Kp[dst + 5] = Kb[src + i5];
  }
}

// ---------------------------------------------------------------------------
// Batched A_full[bh][t][s] = QK_SCALE * Q[t]·K[s], lower-triangular tiles
// only. Same conflict-free fragment split as gemm_f32.
// ---------------------------------------------------------------------------
__global__ __launch_bounds__(256) void qkt_scores(
    const float* __restrict__ Q, const float* __restrict__ K,
    float* __restrict__ Af) {
  if (blockIdx.x > blockIdx.y) return;  // strictly-upper tiles never read
  __shared__ float Qs[16][132];
  __shared__ float Ks[16][132];
  const int bh = blockIdx.z;
  const int tid = threadIdx.x;
  const int tx = tid & 15, ty = tid >> 4;
  const int m0 = blockIdx.y * 128, n0 = blockIdx.x * 128;
  const float* Qb = Q + (size_t)bh * S_LEN * DHEAD;
  const float* Kb = K + (size_t)bh * S_LEN * DHEAD;
  float acc[8][8];
#pragma unroll
  for (int i = 0; i < 8; ++i)
#pragma unroll
    for (int j = 0; j < 8; ++j) acc[i][j] = 0.0f;

  for (int k0 = 0; k0 < DHEAD; k0 += 16) {
#pragma unroll
    for (int l = 0; l < 2; ++l) {
      int f = tid + l * 256;
      int r = f >> 2, c = (f & 3) * 4;
      const float4 q = *(const float4*)&Qb[(size_t)(m0 + r) * DHEAD + k0 + c];
      Qs[c + 0][r] = q.x; Qs[c + 1][r] = q.y;
      Qs[c + 2][r] = q.z; Qs[c + 3][r] = q.w;
      const float4 kv = *(const float4*)&Kb[(size_t)(n0 + r) * DHEAD + k0 + c];
      Ks[c + 0][r] = kv.x; Ks[c + 1][r] = kv.y;
      Ks[c + 2][r] = kv.z; Ks[c + 3][r] = kv.w;
    }
    __syncthreads();
#pragma unroll
    for (int kk = 0; kk < 16; ++kk) {
      float av[8], bv[8];
      *(float4*)&av[0] = *(float4*)&Qs[kk][ty * 4];
      *(float4*)&av[4] = *(float4*)&Qs[kk][64 + ty * 4];
      *(float4*)&bv[0] = *(float4*)&Ks[kk][tx * 4];
      *(float4*)&bv[4] = *(float4*)&Ks[kk][64 + tx * 4];
#pragma unroll
      for (int i = 0; i < 8; ++i)
#pragma unroll
        for (int j = 0; j < 8; ++j) acc[i][j] += av[i] * bv[j];
    }
    __syncthreads();
  }
  float* Cb = Af + (size_t)bh * S_LEN * S_LEN;
#pragma unroll
  for (int gi = 0; gi < 2; ++gi)
#pragma unroll
    for (int i = 0; i < 4; ++i) {
      const int t = m0 + gi * 64 + ty * 4 + i;
#pragma unroll
      for (int gj = 0; gj < 2; ++gj) {
        const int s = n0 + gj * 64 + tx * 4;
        float4 o;
        o.x = acc[gi * 4 + i][gj * 4 + 0] * QK_SCALE;
        o.y = acc[gi * 4 + i][gj * 4 + 1] * QK_SCALE;
        o.z = acc[gi * 4 + i][gj * 4 + 2] * QK_SCALE;
        o.w = acc[gi * 4 + i][gj * 4 + 3] * QK_SCALE;
        *(float4*)&Cb[(size_t)t * S_LEN + s] = o;
      }
    }
}

// ---------------------------------------------------------------------------
// Sequential H2O eviction scan — producer/consumer wave specialization, v2.
// Round-6 failure: a single producer wave using global_load_lds ran the
// 32 DMAs/chunk nearly serially (~17000 cyc/chunk -> LDS-DMA queue depth is
// shallow per CU). v2: TWO producer waves with plain global_load_dwordx4
// into VGPRs (16 loads in flight each, vmcnt-tracked) + ds_write_b128.
// Wave 2 is the consumer: per step, in-lane u64 (sortable-value,s) min gives
// the exact in-lane first-index argmin; cross-lane via ONE fp32 value
// butterfly + ballot; single-candidate fast path (wave-uniform branch) does
// one shfl; exact min-s butterfly fallback on (measure-zero) cross-lane
// value ties -> semantics identical to jnp.argmin. Next row register
// prefetch (distance 1) hides ds_read latency under the butterfly chain.
// Rows consumed: t-1 for t=205..1023 (rows 204..1022), 103 chunks of 8.
// ---------------------------------------------------------------------------
#define SE_CHUNK  8
#define SE_NCHUNK 103

__global__ __launch_bounds__(192, 1) void scan_evict(
    const float* __restrict__ Af, int* __restrict__ evt) {
  __shared__ float buf[2][SE_CHUNK][S_LEN];
  const int bh = blockIdx.x;
  const int tid = threadIdx.x;
  const int lane = tid & 63;
  const int wv = tid >> 6;  // 0,1 = producers, 2 = consumer
  const float* Ab = Af + (size_t)bh * S_LEN * S_LEN;
  int* evtb = evt + bh * S_LEN;

  if (wv < 2) {
    // prologue: stage chunk 0 (rows 204..211); wave wv -> rows wv*4..wv*4+3
    float4 tmp[16];
#pragma unroll
    for (int r = 0; r < 4; ++r) {
      const float* rb = Ab + (size_t)(204 + wv * 4 + r) * S_LEN + lane * 4;
#pragma unroll
      for (int p = 0; p < 4; ++p)
        tmp[r * 4 + p] = *(const float4*)(rb + p * 256);
    }
#pragma unroll
    for (int r = 0; r < 4; ++r)
#pragma unroll
      for (int p = 0; p < 4; ++p)
        *(float4*)&buf[0][wv * 4 + r][p * 256 + lane * 4] = tmp[r * 4 + p];
  } else {
    int4* e4 = (int4*)evtb;
    const int4 big = make_int4(0x7fffffff, 0x7fffffff, 0x7fffffff, 0x7fffffff);
#pragma unroll
    for (int j = 0; j < 4; ++j) e4[j * 64 + lane] = big;
  }
  __syncthreads();

  // lane-owned s values: s = p*256 + lane*4 + q  (slot b = p*4+q)
  int slow[16];
#pragma unroll
  for (int p = 0; p < 4; ++p)
#pragma unroll
    for (int q = 0; q < 4; ++q) slow[p * 4 + q] = p * 256 + lane * 4 + q;
  unsigned evmask = 0;

  for (int c = 0; c < SE_NCHUNK; ++c) {
    if (wv < 2) {
      if (c + 1 < SE_NCHUNK) {
        const int nb = (c + 1) & 1;
        float4 tmp[16];
#pragma unroll
        for (int r = 0; r < 4; ++r) {
          int row = 204 + (c + 1) * SE_CHUNK + wv * 4 + r;
          row = row > 1022 ? 1022 : row;  // tail clamp (never consumed)
          const float* rb = Ab + (size_t)row * S_LEN + lane * 4;
#pragma unroll
          for (int p = 0; p < 4; ++p)
            tmp[r * 4 + p] = *(const float4*)(rb + p * 256);
        }
#pragma unroll
        for (int r = 0; r < 4; ++r)
#pragma unroll
          for (int p = 0; p < 4; ++p)
            *(float4*)&buf[nb][wv * 4 + r][p * 256 + lane * 4] = tmp[r * 4 + p];
      }
    } else {
      const int cb = c & 1;
      float4 cur[4], nxt[4];
#pragma unroll
      for (int p = 0; p < 4; ++p)
        cur[p] = *(const float4*)&buf[cb][0][p * 256 + lane * 4];
#pragma unroll
      for (int u = 0; u < SE_CHUNK; ++u) {
        const int t = 205 + c * SE_CHUNK + u;
        if (t > 1023) break;
        if (u < SE_CHUNK - 1) {
#pragma unroll
          for (int p = 0; p < 4; ++p)
            nxt[p] = *(const float4*)&buf[cb][u + 1][p * 256 + lane * 4];
        }
        const int limit = t - RECENT_B;
        // flush ineligible to +inf
        float fv[16];
#pragma unroll
        for (int p = 0; p < 4; ++p) {
          const float e[4] = {cur[p].x, cur[p].y, cur[p].z, cur[p].w};
#pragma unroll
          for (int q = 0; q < 4; ++q) {
            const int b = p * 4 + q;
            const bool ok = (slow[b] < limit) && !((evmask >> b) & 1u);
            fv[b] = ok ? e[q] : INFINITY;
          }
        }
        // in-lane: f32 value min tree (for the cross-lane butterfly) and
        // exact u64 (sortable value, s) min (first-index tie-break in lane)
        float vt[16];
        unsigned long long k[16];
#pragma unroll
        for (int b = 0; b < 16; ++b) {
          vt[b] = fv[b];
          unsigned su = __float_as_uint(fv[b]);
          su ^= (unsigned)((int)su >> 31) | 0x80000000u;
          k[b] = ((unsigned long long)su << 32) | (unsigned)slow[b];
        }
#pragma unroll
        for (int st = 8; st; st >>= 1)
#pragma unroll
          for (int i = 0; i < 16; ++i)
            if (i < st) {
              vt[i] = fminf(vt[i], vt[i + st]);
              if (k[i + st] < k[i]) k[i] = k[i + st];
            }
        const float vmin = vt[0];
        const int sloc = (int)(unsigned)k[0];
        // single fp32 butterfly for the global min value
        float best = vmin;
#pragma unroll
        for (int off = 32; off; off >>= 1)
          best = fminf(best, __shfl_xor(best, off, 64));
        const unsigned long long mask = __ballot(vmin == best);
        int idx;
        if (__popcll(mask) == 1) {
          idx = __shfl(sloc, (int)__builtin_ctzll(mask), 64);
        } else {  // exact first-index across rare cross-lane value ties
          int cand = (vmin == best) ? sloc : 0x7fffffff;
#pragma unroll
          for (int off = 32; off; off >>= 1)
            cand = min(cand, __shfl_xor(cand, off, 64));
          idx = cand;
        }
        if (((idx & 255) >> 2) == lane)
          evmask |= 1u << (((idx >> 8) << 2) | (idx & 3));
        if (lane == 0) evtb[idx] = t;
#pragma unroll
        for (int p = 0; p < 4; ++p) cur[p] = nxt[p];
      }
    }
    __syncthreads();
  }
}

// ---------------------------------------------------------------------------
// Final attention: 8 query rows per workgroup. Phase 1 (wave per 2 rows):
// score = evicted(s by time t) ? QK_SCALE*dot6(Qp,Kp) : A_full[t][s];
// softmax -> P in LDS + 1/sum. Phase 2: out = (P·V)/sum -> [B,S,HID].
// ---------------------------------------------------------------------------
__global__ __launch_bounds__(256) void attn_av(
    const float* __restrict__ Af, const float* __restrict__ Qp,
    const float* __restrict__ Kp, const int* __restrict__ evt,
    const float* __restrict__ V, float* __restrict__ AO) {
  const int t0 = blockIdx.x * 8;
  const int bh = blockIdx.y;
  __shared__ float P[8][S_LEN];
  __shared__ float rinv[8];
  const int tid = threadIdx.x;
  const int lane = tid & 63, wave = tid >> 6;
  const float* Ab = Af + (size_t)bh * S_LEN * S_LEN;
  const int* eb = evt + bh * S_LEN;
  const float* Kpb = Kp + (size_t)bh * S_LEN * 8;

  for (int rr = 0; rr < 2; ++rr) {
    const int r = wave * 2 + rr;
    const int t = t0 + r;
    float qp[6];
#pragma unroll
    for (int j = 0; j < 6; ++j) qp[j] = Qp[((size_t)bh * S_LEN + t) * 8 + j];
    float vals[16];
    float m = -INFINITY;
#pragma unroll
    for (int i = 0; i < 16; ++i) {
      int s = lane + i * 64;
      float sc = 0.0f;
      if (s <= t) {
        if (eb[s] <= t) {
          const float* kr = &Kpb[(size_t)s * 8];
          sc = QK_SCALE * (qp[0] * kr[0] + qp[1] * kr[1] + qp[2] * kr[2] +
                           qp[3] * kr[3] + qp[4] * kr[4] + qp[5] * kr[5]);
        } else {
          sc = Ab[(size_t)t * S_LEN + s];
        }
        m = fmaxf(m, sc);
      }
      vals[i] = sc;
    }
    for (int off = 32; off; off >>= 1) m = fmaxf(m, __shfl_xor(m, off, 64));
    float sum = 0.0f;
#pragma unroll
    for (int i = 0; i < 16; ++i) {
      int s = lane + i * 64;
      float p = 0.0f;
      if (s <= t) {
        p = expf(vals[i] - m);
        sum += p;
      }
      P[r][s] = p;
    }
    for (int off = 32; off; off >>= 1) sum += __shfl_xor(sum, off, 64);
    if (lane == 0) rinv[r] = 1.0f / sum;
  }
  __syncthreads();

  const int d4 = (tid & 31) * 4;
  const int r = tid >> 5;
  const int t = t0 + r;
  const float* Vb = V + (size_t)bh * S_LEN * DHEAD;
  float ax = 0.f, ay = 0.f, az = 0.f, aw = 0.f;
  const int smax = t0 + 7;
  for (int s4 = 0; s4 <= smax; s4 += 4) {
    const float4 p4 = *(const float4*)&P[r][s4];
    const float4 v0 = *(const float4*)&Vb[(size_t)(s4 + 0) * DHEAD + d4];
    const float4 v1 = *(const float4*)&Vb[(size_t)(s4 + 1) * DHEAD + d4];
    const float4 v2 = *(const float4*)&Vb[(size_t)(s4 + 2) * DHEAD + d4];
    const float4 v3 = *(const float4*)&Vb[(size_t)(s4 + 3) * DHEAD + d4];
    ax += p4.x * v0.x + p4.y * v1.x + p4.z * v2.x + p4.w * v3.x;
    ay += p4.x * v0.y + p4.y * v1.y + p4.z * v2.y + p4.w * v3.y;
    az += p4.x * v0.z + p4.y * v1.z + p4.z * v2.z + p4.w * v3.z;
    aw += p4.x * v0.w + p4.y * v1.w + p4.z * v2.w + p4.w * v3.w;
  }
  const float ri = rinv[r];
  const int b = bh >> 4, h = bh & 15;
  float4 o;
  o.x = ax * ri; o.y = ay * ri; o.z = az * ri; o.w = aw * ri;
  *(float4*)&AO[((size_t)(b * S_LEN + t)) * HIDDEN + h * DHEAD + d4] = o;
}

// ---------------------------------------------------------------------------
extern "C" void kernel_launch(void* const* d_in, const int* in_sizes, int n_in,
                              void* d_out, int out_size, void* d_ws,
                              size_t ws_size, hipStream_t stream) {
  const float* hs = (const float*)d_in[0];
  const float* wq = (const float*)d_in[1];
  const float* wk = (const float*)d_in[2];
  const float* wv = (const float*)d_in[3];
  const float* wo = (const float*)d_in[4];
  float* out = (float*)d_out;

  const size_t SZ_QKV = (size_t)BH * S_LEN * DHEAD;
  float* Q = (float*)d_ws;
  float* K = Q + SZ_QKV;
  float* V = K + SZ_QKV;
  float* Af = V + SZ_QKV;
  float* Qp = Af + (size_t)BH * S_LEN * S_LEN;
  float* Kp = Qp + (size_t)BH * S_LEN * 8;
  int* evt = (int*)(Kp + (size_t)BH * S_LEN * 8);
  float* AO = (float*)(evt + BH * S_LEN);

  gemm_f32<0><<<dim3(16, 16, 3), 256, 0, stream>>>(hs, wq, wk, wv, Q, K, V);
  rope_qk<<<dim3(BH * S_LEN / 4), 256, 0, stream>>>(Q, K);
  keep_pack<<<dim3(BH), 128, 0, stream>>>(Q, K, Qp, Kp);
  qkt_scores<<<dim3(8, 8, BH), 256, 0, stream>>>(Q, K, Af);
  scan_evict<<<dim3(BH), 192, 0, stream>>>(Af, evt);
  attn_av<<<dim3(S_LEN / 8, BH), 256, 0, stream>>>(Af, Qp, Kp, evt, V, AO);
  gemm_f32<1><<<dim3(16, 16, 1), 256, 0, stream>>>(AO, wo, nullptr, nullptr,
                                                   out, nullptr, nullptr);
}

// Round 9
// 1992.414 us; speedup vs baseline: 1.0942x; 1.0043x over previous
//
#include <hip/hip_runtime.h>
#include <math.h>

// Problem constants (fixed by reference)
#define S_LEN    1024
#define NHEAD    16
#define DHEAD    128
#define HIDDEN   2048
#define BATCH    2
#define BH       32            // BATCH*NHEAD
#define CACHE_B  204           // heavy+recent budget
#define RECENT_B 102
#define QK_SCALE 0.08838834764831845f   // 1/sqrt(128)

typedef float v2f __attribute__((ext_vector_type(2)));

// ---------------------------------------------------------------------------
// Tiled fp32 GEMM, 128x128 tile, 256 threads, 8x8 per thread, PACKED fp32:
// inner product over float2 ext-vectors so clang emits v_pk_fma_f32
// (2 FLOP/lane/instr -> 2x the scalar 157 TF vector roofline we measured).
// Fragment split rows {ty*4, 64+ty*4}, cols {tx*4, 64+tx*4}: LDS reads
// <=2-way bank aliased (free); pad 132 keeps As stores 2-way.
// MODE 0: C = hs @ {wq|wk|wv} (blockIdx.z), epilogue scatters to [B,H,S,D].
// MODE 1: plain row-major C = A @ B0.
// ---------------------------------------------------------------------------
template <int MODE>
__global__ __launch_bounds__(256) void gemm_f32(
    const float* __restrict__ A, const float* __restrict__ B0,
    const float* __restrict__ B1, const float* __restrict__ B2,
    float* __restrict__ C0, float* __restrict__ C1, float* __restrict__ C2) {
  __shared__ float As[16][132];
  __shared__ float Bs[16][132];
  const float* Bm;
  float* C;
  if (MODE == 0) {
    int z = blockIdx.z;
    Bm = (z == 0) ? B0 : ((z == 1) ? B1 : B2);
    C = (z == 0) ? C0 : ((z == 1) ? C1 : C2);
  } else {
    Bm = B0;
    C = C0;
  }
  const int tid = threadIdx.x;
  const int tx = tid & 15, ty = tid >> 4;
  const int m0 = blockIdx.y * 128, n0 = blockIdx.x * 128;

  v2f acc[8][4];
#pragma unroll
  for (int i = 0; i < 8; ++i)
#pragma unroll
    for (int p = 0; p < 4; ++p) acc[i][p] = (v2f)(0.0f);

  for (int k0 = 0; k0 < HIDDEN; k0 += 16) {
#pragma unroll
    for (int l = 0; l < 2; ++l) {
      int f = tid + l * 256;
      int r = f >> 2, c = (f & 3) * 4;
      const float4 a =
          *(const float4*)&A[(size_t)(m0 + r) * HIDDEN + k0 + c];
      As[c + 0][r] = a.x;
      As[c + 1][r] = a.y;
      As[c + 2][r] = a.z;
      As[c + 3][r] = a.w;
    }
#pragma unroll
    for (int l = 0; l < 2; ++l) {
      int f = tid + l * 256;
      int r = f >> 5, c = (f & 31) * 4;
      *(float4*)&Bs[r][c] =
          *(const float4*)&Bm[(size_t)(k0 + r) * HIDDEN + n0 + c];
    }
    __syncthreads();
#pragma unroll
    for (int kk = 0; kk < 16; ++kk) {
      float av[8];
      v2f bv[4];
      *(float4*)&av[0] = *(float4*)&As[kk][ty * 4];
      *(float4*)&av[4] = *(float4*)&As[kk][64 + ty * 4];
      const float4 b0 = *(const float4*)&Bs[kk][tx * 4];
      const float4 b1 = *(const float4*)&Bs[kk][64 + tx * 4];
      bv[0] = (v2f){b0.x, b0.y};
      bv[1] = (v2f){b0.z, b0.w};
      bv[2] = (v2f){b1.x, b1.y};
      bv[3] = (v2f){b1.z, b1.w};
#pragma unroll
      for (int i = 0; i < 8; ++i) {
        const v2f a2 = (v2f){av[i], av[i]};
#pragma unroll
        for (int p = 0; p < 4; ++p) acc[i][p] = a2 * bv[p] + acc[i][p];
      }
    }
    __syncthreads();
  }

#pragma unroll
  for (int gi = 0; gi < 2; ++gi)
#pragma unroll
    for (int i = 0; i < 4; ++i) {
      const int m = m0 + gi * 64 + ty * 4 + i;
      const int ia = gi * 4 + i;
#pragma unroll
      for (int gj = 0; gj < 2; ++gj) {
        const int n = n0 + gj * 64 + tx * 4;
        float4 o;
        o.x = acc[ia][gj * 2 + 0].x;
        o.y = acc[ia][gj * 2 + 0].y;
        o.z = acc[ia][gj * 2 + 1].x;
        o.w = acc[ia][gj * 2 + 1].y;
        if (MODE == 0) {
          const int b = m >> 10, s = m & (S_LEN - 1);
          const int h = n >> 7, d = n & (DHEAD - 1);
          *(float4*)&C[(((size_t)(b * NHEAD + h) * S_LEN + s) * DHEAD) + d] = o;
        } else {
          *(float4*)&C[(size_t)m * HIDDEN + n] = o;
        }
      }
    }
}

// ---------------------------------------------------------------------------
// RoPE in place on Q,K ([BH,S,D] layout).
// ---------------------------------------------------------------------------
__global__ __launch_bounds__(256) void rope_qk(float* __restrict__ Q,
                                               float* __restrict__ K) {
  int g = blockIdx.x * 4 + (threadIdx.x >> 6);  // row id over BH*S
  int lane = threadIdx.x & 63;
  int s = g & (S_LEN - 1);
  double invf = exp(-((double)(2 * lane) / 128.0) * log(10000.0));
  float angle = (float)s * (float)invf;
  float c = (float)cos((double)angle);
  float sn = (float)sin((double)angle);
  size_t base = (size_t)g * DHEAD;
  float q0 = Q[base + lane], q1 = Q[base + lane + 64];
  Q[base + lane] = q0 * c - q1 * sn;
  Q[base + lane + 64] = q1 * c + q0 * sn;
  float k0 = K[base + lane], k1 = K[base + lane + 64];
  K[base + lane] = k0 * c - k1 * sn;
  K[base + lane + 64] = k1 * c + k0 * sn;
}

// ---------------------------------------------------------------------------
// Per (b,h): mean |k| over first 204 roped tokens, stable argsort rank,
// keep top-6 dims; pack Qp/Kp[bh][s][0..5] (stride 8).
// ---------------------------------------------------------------------------
__global__ __launch_bounds__(128) void keep_pack(
    const float* __restrict__ Q, const float* __restrict__ K,
    float* __restrict__ Qp, float* __restrict__ Kp) {
  int bh = blockIdx.x;
  int d = threadIdx.x;
  __shared__ float ma[128];
  __shared__ int kf[128];
  __shared__ int kidx[8];
  const float* Kb = K + (size_t)bh * S_LEN * DHEAD;
  const float* Qb = Q + (size_t)bh * S_LEN * DHEAD;
  float sum = 0.0f;
  for (int s = 0; s < CACHE_B; ++s) sum += fabsf(Kb[(size_t)s * DHEAD + d]);
  ma[d] = sum / 204.0f;
  __syncthreads();
  float v = ma[d];
  int rank = 0;
  for (int e = 0; e < 128; ++e) {
    float u = ma[e];
    rank += (u < v) || (u == v && e < d);  // stable-argsort rank
  }
  int keep = (rank >= 128 - 6);
  kf[d] = keep;
  __syncthreads();
  if (keep) {
    int pos = 0;
    for (int e = 0; e < d; ++e) pos += kf[e];
    kidx[pos] = d;
  }
  __syncthreads();
  int i0 = kidx[0], i1 = kidx[1], i2 = kidx[2];
  int i3 = kidx[3], i4 = kidx[4], i5 = kidx[5];
  for (int s = threadIdx.x; s < S_LEN; s += 128) {
    size_t src = (size_t)s * DHEAD;
    size_t dst = ((size_t)bh * S_LEN + s) * 8;
    Qp[dst + 0] = Qb[src + i0]; Qp[dst + 1] = Qb[src + i1];
    Qp[dst + 2] = Qb[src + i2]; Qp[dst + 3] = Qb[src + i3];
    Qp[dst + 4] = Qb[src + i4]; Qp[dst + 5] = Qb[src + i5];
    Kp[dst + 0] = Kb[src + i0]; Kp[dst + 1] = Kb[src + i1];
    Kp[dst + 2] = Kb[src + i2]; Kp[dst + 3] = Kb[src + i3];
    Kp[dst + 4] = Kb[src + i4]; Kp[dst + 5] = Kb[src + i5];
  }
}

// ---------------------------------------------------------------------------
// Batched A_full[bh][t][s] = QK_SCALE * Q[t]·K[s], lower-triangular tiles
// only. Same conflict-free fragment split + packed fp32 as gemm_f32.
// ---------------------------------------------------------------------------
__global__ __launch_bounds__(256) void qkt_scores(
    const float* __restrict__ Q, const float* __restrict__ K,
    float* __restrict__ Af) {
  if (blockIdx.x > blockIdx.y) return;  // strictly-upper tiles never read
  __shared__ float Qs[16][132];
  __shared__ float Ks[16][132];
  const int bh = blockIdx.z;
  const int tid = threadIdx.x;
  const int tx = tid & 15, ty = tid >> 4;
  const int m0 = blockIdx.y * 128, n0 = blockIdx.x * 128;
  const float* Qb = Q + (size_t)bh * S_LEN * DHEAD;
  const float* Kb = K + (size_t)bh * S_LEN * DHEAD;
  v2f acc[8][4];
#pragma unroll
  for (int i = 0; i < 8; ++i)
#pragma unroll
    for (int p = 0; p < 4; ++p) acc[i][p] = (v2f)(0.0f);

  for (int k0 = 0; k0 < DHEAD; k0 += 16) {
#pragma unroll
    for (int l = 0; l < 2; ++l) {
      int f = tid + l * 256;
      int r = f >> 2, c = (f & 3) * 4;
      const float4 q = *(const float4*)&Qb[(size_t)(m0 + r) * DHEAD + k0 + c];
      Qs[c + 0][r] = q.x; Qs[c + 1][r] = q.y;
      Qs[c + 2][r] = q.z; Qs[c + 3][r] = q.w;
      const float4 kv = *(const float4*)&Kb[(size_t)(n0 + r) * DHEAD + k0 + c];
      Ks[c + 0][r] = kv.x; Ks[c + 1][r] = kv.y;
      Ks[c + 2][r] = kv.z; Ks[c + 3][r] = kv.w;
    }
    __syncthreads();
#pragma unroll
    for (int kk = 0; kk < 16; ++kk) {
      float av[8];
      v2f bv[4];
      *(float4*)&av[0] = *(float4*)&Qs[kk][ty * 4];
      *(float4*)&av[4] = *(float4*)&Qs[kk][64 + ty * 4];
      const float4 b0 = *(const float4*)&Ks[kk][tx * 4];
      const float4 b1 = *(const float4*)&Ks[kk][64 + tx * 4];
      bv[0] = (v2f){b0.x, b0.y};
      bv[1] = (v2f){b0.z, b0.w};
      bv[2] = (v2f){b1.x, b1.y};
      bv[3] = (v2f){b1.z, b1.w};
#pragma unroll
      for (int i = 0; i < 8; ++i) {
        const v2f a2 = (v2f){av[i], av[i]};
#pragma unroll
        for (int p = 0; p < 4; ++p) acc[i][p] = a2 * bv[p] + acc[i][p];
      }
    }
    __syncthreads();
  }
  float* Cb = Af + (size_t)bh * S_LEN * S_LEN;
#pragma unroll
  for (int gi = 0; gi < 2; ++gi)
#pragma unroll
    for (int i = 0; i < 4; ++i) {
      const int t = m0 + gi * 64 + ty * 4 + i;
      const int ia = gi * 4 + i;
#pragma unroll
      for (int gj = 0; gj < 2; ++gj) {
        const int s = n0 + gj * 64 + tx * 4;
        float4 o;
        o.x = acc[ia][gj * 2 + 0].x * QK_SCALE;
        o.y = acc[ia][gj * 2 + 0].y * QK_SCALE;
        o.z = acc[ia][gj * 2 + 1].x * QK_SCALE;
        o.w = acc[ia][gj * 2 + 1].y * QK_SCALE;
        *(float4*)&Cb[(size_t)t * S_LEN + s] = o;
      }
    }
}

// ---------------------------------------------------------------------------
// Sequential H2O eviction scan — producer/consumer waves + DPP reductions.
// Round-7 finding: consumer step ~1880 cyc, dominated by ~13 dependent
// ds_bpermute round-trips (shfl/ballot). v3 replaces ALL cross-lane traffic
// with the canonical GCN DPP min-reduce (row_shr 1/2/4/8 + row_bcast 15/31,
// VALU pipe, ~5 cyc/hop) + readlane(63). DPP ctrl/masks are TEMPLATE
// parameters (round-8 failure: __builtin_amdgcn_update_dpp requires
// integer-constant args; runtime function params don't compile).
//   best = wave_min_f32(in-lane min of eligible values)      [wave-uniform]
//   idx  = wave_min_i32(in-lane min s among {s: v==best})    [wave-uniform]
// min-index-among-minima == first-index argmin — exactly jnp.argmin.
// Producers (2 waves) stage 8-row chunks via global_load_dwordx4 +
// ds_write_b128 (16 loads in flight each); double-buffered, 1 barrier/chunk.
// ---------------------------------------------------------------------------
#define SE_CHUNK  8
#define SE_NCHUNK 103

template <int CTRL, int RMASK>
__device__ __forceinline__ float dpp_fmin(float x) {
  const int xi = __builtin_bit_cast(int, x);
  const int y = __builtin_amdgcn_update_dpp(xi, xi, CTRL, RMASK, 0xF, false);
  return fminf(x, __builtin_bit_cast(float, y));
}
__device__ __forceinline__ float wave_min_f32(float x) {
  x = dpp_fmin<0x111, 0xF>(x);  // row_shr:1
  x = dpp_fmin<0x112, 0xF>(x);  // row_shr:2
  x = dpp_fmin<0x114, 0xF>(x);  // row_shr:4
  x = dpp_fmin<0x118, 0xF>(x);  // row_shr:8
  x = dpp_fmin<0x142, 0xA>(x);  // row_bcast:15
  x = dpp_fmin<0x143, 0xC>(x);  // row_bcast:31
  return __builtin_bit_cast(
      float, __builtin_amdgcn_readlane(__builtin_bit_cast(int, x), 63));
}
template <int CTRL, int RMASK>
__device__ __forceinline__ int dpp_imin(int x) {
  const int y = __builtin_amdgcn_update_dpp(x, x, CTRL, RMASK, 0xF, false);
  return min(x, y);
}
__device__ __forceinline__ int wave_min_i32(int x) {
  x = dpp_imin<0x111, 0xF>(x);
  x = dpp_imin<0x112, 0xF>(x);
  x = dpp_imin<0x114, 0xF>(x);
  x = dpp_imin<0x118, 0xF>(x);
  x = dpp_imin<0x142, 0xA>(x);
  x = dpp_imin<0x143, 0xC>(x);
  return __builtin_amdgcn_readlane(x, 63);
}

__global__ __launch_bounds__(192, 1) void scan_evict(
    const float* __restrict__ Af, int* __restrict__ evt) {
  __shared__ float buf[2][SE_CHUNK][S_LEN];
  const int bh = blockIdx.x;
  const int tid = threadIdx.x;
  const int lane = tid & 63;
  const int wv = tid >> 6;  // 0,1 = producers, 2 = consumer
  const float* Ab = Af + (size_t)bh * S_LEN * S_LEN;
  int* evtb = evt + bh * S_LEN;

  if (wv < 2) {
    // prologue: stage chunk 0 (rows 204..211); wave wv -> rows wv*4..wv*4+3
    float4 tmp[16];
#pragma unroll
    for (int r = 0; r < 4; ++r) {
      const float* rb = Ab + (size_t)(204 + wv * 4 + r) * S_LEN + lane * 4;
#pragma unroll
      for (int p = 0; p < 4; ++p)
        tmp[r * 4 + p] = *(const float4*)(rb + p * 256);
    }
#pragma unroll
    for (int r = 0; r < 4; ++r)
#pragma unroll
      for (int p = 0; p < 4; ++p)
        *(float4*)&buf[0][wv * 4 + r][p * 256 + lane * 4] = tmp[r * 4 + p];
  } else {
    int4* e4 = (int4*)evtb;
    const int4 big = make_int4(0x7fffffff, 0x7fffffff, 0x7fffffff, 0x7fffffff);
#pragma unroll
    for (int j = 0; j < 4; ++j) e4[j * 64 + lane] = big;
  }
  __syncthreads();

  // lane-owned s values: s = p*256 + lane*4 + q  (slot b = p*4+q)
  int slow[16];
#pragma unroll
  for (int p = 0; p < 4; ++p)
#pragma unroll
    for (int q = 0; q < 4; ++q) slow[p * 4 + q] = p * 256 + lane * 4 + q;
  unsigned evmask = 0;

  for (int c = 0; c < SE_NCHUNK; ++c) {
    if (wv < 2) {
      if (c + 1 < SE_NCHUNK) {
        const int nb = (c + 1) & 1;
        float4 tmp[16];
#pragma unroll
        for (int r = 0; r < 4; ++r) {
          int row = 204 + (c + 1) * SE_CHUNK + wv * 4 + r;
          row = row > 1022 ? 1022 : row;  // tail clamp (never consumed)
          const float* rb = Ab + (size_t)row * S_LEN + lane * 4;
#pragma unroll
          for (int p = 0; p < 4; ++p)
            tmp[r * 4 + p] = *(const float4*)(rb + p * 256);
        }
#pragma unroll
        for (int r = 0; r < 4; ++r)
#pragma unroll
          for (int p = 0; p < 4; ++p)
            *(float4*)&buf[nb][wv * 4 + r][p * 256 + lane * 4] = tmp[r * 4 + p];
      }
    } else {
      const int cb = c & 1;
      float4 cur[4], nxt[4];
#pragma unroll
      for (int p = 0; p < 4; ++p)
        cur[p] = *(const float4*)&buf[cb][0][p * 256 + lane * 4];
#pragma unroll
      for (int u = 0; u < SE_CHUNK; ++u) {
        const int t = 205 + c * SE_CHUNK + u;
        if (t > 1023) break;
        if (u < SE_CHUNK - 1) {
#pragma unroll
          for (int p = 0; p < 4; ++p)
            nxt[p] = *(const float4*)&buf[cb][u + 1][p * 256 + lane * 4];
        }
        const int limit = t - RECENT_B;
        // flush ineligible to +inf; in-lane min
        float fv[16];
        float vmin = INFINITY;
#pragma unroll
        for (int p = 0; p < 4; ++p) {
          const float e[4] = {cur[p].x, cur[p].y, cur[p].z, cur[p].w};
#pragma unroll
          for (int q = 0; q < 4; ++q) {
            const int b = p * 4 + q;
            const bool ok = (slow[b] < limit) && !((evmask >> b) & 1u);
            fv[b] = ok ? e[q] : INFINITY;
            vmin = fminf(vmin, fv[b]);
          }
        }
        const float best = wave_min_f32(vmin);  // wave-uniform global min
        // first index among minima (exact jnp.argmin tie semantics)
        int cand = 0x7fffffff;
#pragma unroll
        for (int b = 0; b < 16; ++b)
          cand = (fv[b] == best) ? min(cand, slow[b]) : cand;
        const int idx = wave_min_i32(cand);     // wave-uniform
        if (((idx & 255) >> 2) == lane)
          evmask |= 1u << (((idx >> 8) << 2) | (idx & 3));
        if (lane == 0) evtb[idx] = t;
#pragma unroll
        for (int p = 0; p < 4; ++p) cur[p] = nxt[p];
      }
    }
    __syncthreads();
  }
}

// ---------------------------------------------------------------------------
// Final attention: 8 query rows per workgroup. Phase 1 (wave per 2 rows):
// score = evicted(s by time t) ? QK_SCALE*dot6(Qp,Kp) : A_full[t][s];
// softmax -> P in LDS + 1/sum. Phase 2: out = (P·V)/sum -> [B,S,HID].
// ---------------------------------------------------------------------------
__global__ __launch_bounds__(256) void attn_av(
    const float* __restrict__ Af, const float* __restrict__ Qp,
    const float* __restrict__ Kp, const int* __restrict__ evt,
    const float* __restrict__ V, float* __restrict__ AO) {
  const int t0 = blockIdx.x * 8;
  const int bh = blockIdx.y;
  __shared__ float P[8][S_LEN];
  __shared__ float rinv[8];
  const int tid = threadIdx.x;
  const int lane = tid & 63, wave = tid >> 6;
  const float* Ab = Af + (size_t)bh * S_LEN * S_LEN;
  const int* eb = evt + bh * S_LEN;
  const float* Kpb = Kp + (size_t)bh * S_LEN * 8;

  for (int rr = 0; rr < 2; ++rr) {
    const int r = wave * 2 + rr;
    const int t = t0 + r;
    float qp[6];
#pragma unroll
    for (int j = 0; j < 6; ++j) qp[j] = Qp[((size_t)bh * S_LEN + t) * 8 + j];
    float vals[16];
    float m = -INFINITY;
#pragma unroll
    for (int i = 0; i < 16; ++i) {
      int s = lane + i * 64;
      float sc = 0.0f;
      if (s <= t) {
        if (eb[s] <= t) {
          const float* kr = &Kpb[(size_t)s * 8];
          sc = QK_SCALE * (qp[0] * kr[0] + qp[1] * kr[1] + qp[2] * kr[2] +
                           qp[3] * kr[3] + qp[4] * kr[4] + qp[5] * kr[5]);
        } else {
          sc = Ab[(size_t)t * S_LEN + s];
        }
        m = fmaxf(m, sc);
      }
      vals[i] = sc;
    }
    for (int off = 32; off; off >>= 1) m = fmaxf(m, __shfl_xor(m, off, 64));
    float sum = 0.0f;
#pragma unroll
    for (int i = 0; i < 16; ++i) {
      int s = lane + i * 64;
      float p = 0.0f;
      if (s <= t) {
        p = expf(vals[i] - m);
        sum += p;
      }
      P[r][s] = p;
    }
    for (int off = 32; off; off >>= 1) sum += __shfl_xor(sum, off, 64);
    if (lane == 0) rinv[r] = 1.0f / sum;
  }
  __syncthreads();

  const int d4 = (tid & 31) * 4;
  const int r = tid >> 5;
  const int t = t0 + r;
  const float* Vb = V + (size_t)bh * S_LEN * DHEAD;
  float ax = 0.f, ay = 0.f, az = 0.f, aw = 0.f;
  const int smax = t0 + 7;
  for (int s4 = 0; s4 <= smax; s4 += 4) {
    const float4 p4 = *(const float4*)&P[r][s4];
    const float4 v0 = *(const float4*)&Vb[(size_t)(s4 + 0) * DHEAD + d4];
    const float4 v1 = *(const float4*)&Vb[(size_t)(s4 + 1) * DHEAD + d4];
    const float4 v2 = *(const float4*)&Vb[(size_t)(s4 + 2) * DHEAD + d4];
    const float4 v3 = *(const float4*)&Vb[(size_t)(s4 + 3) * DHEAD + d4];
    ax += p4.x * v0.x + p4.y * v1.x + p4.z * v2.x + p4.w * v3.x;
    ay += p4.x * v0.y + p4.y * v1.y + p4.z * v2.y + p4.w * v3.y;
    az += p4.x * v0.z + p4.y * v1.z + p4.z * v2.z + p4.w * v3.z;
    aw += p4.x * v0.w + p4.y * v1.w + p4.z * v2.w + p4.w * v3.w;
  }
  const float ri = rinv[r];
  const int b = bh >> 4, h = bh & 15;
  float4 o;
  o.x = ax * ri; o.y = ay * ri; o.z = az * ri; o.w = aw * ri;
  *(float4*)&AO[((size_t)(b * S_LEN + t)) * HIDDEN + h * DHEAD + d4] = o;
}

// ---------------------------------------------------------------------------
extern "C" void kernel_launch(void* const* d_in, const int* in_sizes, int n_in,
                              void* d_out, int out_size, void* d_ws,
                              size_t ws_size, hipStream_t stream) {
  const float* hs = (const float*)d_in[0];
  const float* wq = (const float*)d_in[1];
  const float* wk = (const float*)d_in[2];
  const float* wv = (const float*)d_in[3];
  const float* wo = (const float*)d_in[4];
  float* out = (float*)d_out;

  const size_t SZ_QKV = (size_t)BH * S_LEN * DHEAD;
  float* Q = (float*)d_ws;
  float* K = Q + SZ_QKV;
  float* V = K + SZ_QKV;
  float* Af = V + SZ_QKV;
  float* Qp = Af + (size_t)BH * S_LEN * S_LEN;
  float* Kp = Qp + (size_t)BH * S_LEN * 8;
  int* evt = (int*)(Kp + (size_t)BH * S_LEN * 8);
  float* AO = (float*)(evt + BH * S_LEN);

  gemm_f32<0><<<dim3(16, 16, 3), 256, 0, stream>>>(hs, wq, wk, wv, Q, K, V);
  rope_qk<<<dim3(BH * S_LEN / 4), 256, 0, stream>>>(Q, K);
  keep_pack<<<dim3(BH), 128, 0, stream>>>(Q, K, Qp, Kp);
  qkt_scores<<<dim3(8, 8, BH), 256, 0, stream>>>(Q, K, Af);
  scan_evict<<<dim3(BH), 192, 0, stream>>>(Af, evt);
  attn_av<<<dim3(S_LEN / 8, BH), 256, 0, stream>>>(Af, Qp, Kp, evt, V, AO);
  gemm_f32<1><<<dim3(16, 16, 1), 256, 0, stream>>>(AO, wo, nullptr, nullptr,
                                                   out, nullptr, nullptr);
}